// Round 1
// baseline (85.042 us; speedup 1.0000x reference)
//
#include <hip/hip_runtime.h>

#define PPT 4
#define BLOCK 256

// ws layout (floats):
//   [0    .. 4095] : per-batch packed W1: 8 batches x 128 hidden x float4 {w0,w1,w2, b1+w3*theta_b}
//   [4096 .. 4351] : packed W2: 128 x float2 {W2[0][h], W2[1][h]}
//   [4352 .. 4359] : cos(theta_b)
//   [4360 .. 4367] : sin(theta_b)
//   [4368 .. 4375] : theta_b
// total 17504 bytes

__global__ void prep_kernel(const float* __restrict__ latent,
                            const float* __restrict__ W1,
                            const float* __restrict__ b1,
                            const float* __restrict__ W2,
                            float* __restrict__ ws) {
    const int t = threadIdx.x;          // 1024 threads = 8 batches x 128 hidden
    const int b = t >> 7;
    const int h = t & 127;
    const float theta = latent[b] * 10.0f;
    float4 w;
    w.x = W1[h * 4 + 0];
    w.y = W1[h * 4 + 1];
    w.z = W1[h * 4 + 2];
    w.w = fmaf(W1[h * 4 + 3], theta, b1[h]);   // fold theta term into bias
    reinterpret_cast<float4*>(ws)[b * 128 + h] = w;
    if (b == 0) {
        reinterpret_cast<float2*>(ws + 4096)[h] = make_float2(W2[h], W2[128 + h]);
        if (h < 8) {
            const float th = latent[h] * 10.0f;
            ws[4352 + h] = cosf(th);
            ws[4360 + h] = sinf(th);
            ws[4368 + h] = th;
        }
    }
}

__global__ __launch_bounds__(BLOCK) void cubeflow_kernel(
    const float* __restrict__ input, const float* __restrict__ ws,
    const float* __restrict__ b2g, float* __restrict__ out) {
    const int base  = blockIdx.x * (BLOCK * PPT);
    const int batch = base >> 16;                       // P = 65536
    const float4* __restrict__ wp  = reinterpret_cast<const float4*>(ws) + batch * 128;
    const float2* __restrict__ w2p = reinterpret_cast<const float2*>(ws + 4096);
    const float cth   = ws[4352 + batch];
    const float sth   = ws[4360 + batch];
    const float theta = ws[4368 + batch];
    const float b2_0 = b2g[0];
    const float b2_1 = b2g[1];

    const int p0 = base + threadIdx.x * PPT;

    // 48 contiguous bytes per thread = 3 x float4 (12 floats = 4 points x 3 coords)
    const float4 i0 = *reinterpret_cast<const float4*>(input + p0 * 3);
    const float4 i1 = *reinterpret_cast<const float4*>(input + p0 * 3 + 4);
    const float4 i2 = *reinterpret_cast<const float4*>(input + p0 * 3 + 8);
    float x0[PPT] = {i0.x, i0.w, i1.z, i2.y};
    float x1[PPT] = {i0.y, i1.x, i1.w, i2.z};
    float x2[PPT] = {i0.z, i1.y, i2.x, i2.w};

    float* __restrict__ out_eval  = out;                 // 524288 floats
    float* __restrict__ out_con   = out + 524288;        // 524288 * 4
    float* __restrict__ out_probs = out + 2621440;       // 524288 * 2

    // ---- eval (closed-form Rz quadratics) + con store ----
    float ev[PPT];
#pragma unroll
    for (int k = 0; k < PPT; ++k) {
        const float d0 = x0[k] - theta;
        const float d1 = x1[k];
        const float d2 = x2[k];
        const float f1 = fmaf(1.4f * d0, d0, fmaf(1.4f * d1, d1, 0.2f * d2 * d2)) - 0.5f;
        const float c2x = fmaf(cth, d0,  sth * d1);
        const float c2y = fmaf(cth, d1, -sth * d0);
        const float c2z = d2 + 0.4f;
        const float f2 = fmaf(3.8f * c2x, c2x, fmaf(0.6f * c2y, c2y, 3.8f * c2z * c2z)) - 0.5f;
        const float c3x = fmaf(cth, d0, -sth * d1);
        const float c3y = fmaf(sth, d0,  cth * d1);
        const float c3z = d2 - 0.6f;
        const float f3 = fmaf(0.35f * c3x, c3x, fmaf(2.8f * c3y, c3y, 2.8f * c3z * c3z)) - 0.5f;
        ev[k] = fminf(f1, fminf(f2, f3));
        *reinterpret_cast<float4*>(out_con + (p0 + k) * 4) =
            make_float4(x0[k], x1[k], x2[k], theta);
    }
    *reinterpret_cast<float4*>(out_eval + p0) = make_float4(ev[0], ev[1], ev[2], ev[3]);

    // ---- MLP: h = relu(W1[:, :3] @ x + b1eff); probs = W2 @ h + b2 ----
    float a0[PPT], a1[PPT];
#pragma unroll
    for (int k = 0; k < PPT; ++k) { a0[k] = b2_0; a1[k] = b2_1; }

#pragma unroll 8
    for (int h = 0; h < 128; ++h) {
        const float4 w  = wp[h];    // uniform address -> s_load
        const float2 w2 = w2p[h];   // uniform address -> s_load
#pragma unroll
        for (int k = 0; k < PPT; ++k) {
            float hv = fmaf(x0[k], w.x, fmaf(x1[k], w.y, fmaf(x2[k], w.z, w.w)));
            hv = fmaxf(hv, 0.0f);
            a0[k] = fmaf(hv, w2.x, a0[k]);
            a1[k] = fmaf(hv, w2.y, a1[k]);
        }
    }

#pragma unroll
    for (int k = 0; k < PPT; k += 2) {
        *reinterpret_cast<float4*>(out_probs + (p0 + k) * 2) =
            make_float4(a0[k], a1[k], a0[k + 1], a1[k + 1]);
    }
}

extern "C" void kernel_launch(void* const* d_in, const int* in_sizes, int n_in,
                              void* d_out, int out_size, void* d_ws, size_t ws_size,
                              hipStream_t stream) {
    const float* input  = (const float*)d_in[0];
    const float* latent = (const float*)d_in[1];
    const float* W1     = (const float*)d_in[2];
    const float* b1     = (const float*)d_in[3];
    const float* W2     = (const float*)d_in[4];
    const float* b2     = (const float*)d_in[5];
    float* ws  = (float*)d_ws;
    float* out = (float*)d_out;

    hipLaunchKernelGGL(prep_kernel, dim3(1), dim3(1024), 0, stream,
                       latent, W1, b1, W2, ws);

    const int n_points = 8 * 65536;
    const int nblocks  = n_points / (BLOCK * PPT);   // 512
    hipLaunchKernelGGL(cubeflow_kernel, dim3(nblocks), dim3(BLOCK), 0, stream,
                       input, ws, b2, out);
}

// Round 2
// 83.790 us; speedup vs baseline: 1.0149x; 1.0149x over previous
//
#include <hip/hip_runtime.h>

#define BLOCK 256
#define PPT 4
#define NPTS (8 * 65536)

// Single fused kernel.
// Point assignment is STRIDED: thread t in block b owns points
//   p(k) = b*1024 + t + k*256, k = 0..3
// so every global load/store instruction is lane-contiguous:
//   input  : dwordx3 per point, 12B lane stride (wave covers 768B contiguous)
//   eval   : dword,   4B lane stride
//   con    : dwordx4, 16B lane stride
//   probs  : dwordx2, 8B lane stride
// Weights are read at wave-uniform, h-sequential addresses -> scalar loads
// (SMEM pipe), keeping VMEM out of the inner loop.

__global__ __launch_bounds__(BLOCK) void cubeflow_fused(
    const float* __restrict__ input,
    const float* __restrict__ latent,
    const float* __restrict__ W1,
    const float* __restrict__ b1,
    const float* __restrict__ W2,
    const float* __restrict__ b2,
    float* __restrict__ out)
{
    const int base  = blockIdx.x * (BLOCK * PPT);
    const int batch = base >> 16;              // P = 65536, 64 blocks per batch
    const float theta = latent[batch] * 10.0f; // uniform
    const float cth = __cosf(theta);
    const float sth = __sinf(theta);
    const float b20 = b2[0];
    const float b21 = b2[1];

    const int t = threadIdx.x;

    int   p[PPT];
    float x0[PPT], x1[PPT], x2[PPT];
#pragma unroll
    for (int k = 0; k < PPT; ++k) {
        p[k] = base + t + k * BLOCK;
        const float* ip = input + 3 * p[k];    // 12B lane stride, contiguous
        x0[k] = ip[0];
        x1[k] = ip[1];
        x2[k] = ip[2];
    }

    float* __restrict__ out_eval  = out;                // NPTS floats
    float* __restrict__ out_con   = out + NPTS;         // NPTS*4 floats
    float* __restrict__ out_probs = out + 5 * NPTS;     // NPTS*2 floats

    // ---- eval (closed-form Rz quadratics) + con store ----
#pragma unroll
    for (int k = 0; k < PPT; ++k) {
        const float d0 = x0[k] - theta;
        const float d1 = x1[k];
        const float d2 = x2[k];
        const float f1 = fmaf(1.4f * d0, d0, fmaf(1.4f * d1, d1, 0.2f * d2 * d2)) - 0.5f;
        const float c2x = fmaf(cth, d0,  sth * d1);
        const float c2y = fmaf(cth, d1, -sth * d0);
        const float c2z = d2 + 0.4f;
        const float f2 = fmaf(3.8f * c2x, c2x, fmaf(0.6f * c2y, c2y, 3.8f * c2z * c2z)) - 0.5f;
        const float c3x = fmaf(cth, d0, -sth * d1);
        const float c3y = fmaf(sth, d0,  cth * d1);
        const float c3z = d2 - 0.6f;
        const float f3 = fmaf(0.35f * c3x, c3x, fmaf(2.8f * c3y, c3y, 2.8f * c3z * c3z)) - 0.5f;
        const float ev = fminf(f1, fminf(f2, f3));

        out_eval[p[k]] = ev;                                       // coalesced dword
        *reinterpret_cast<float4*>(out_con + 4 * p[k]) =
            make_float4(x0[k], x1[k], x2[k], theta);               // coalesced dwordx4
    }

    // ---- MLP: h = relu(W1[:, :3]x + (b1 + theta*W1[:,3])); probs = W2 h + b2 ----
    float a0[PPT], a1[PPT];
#pragma unroll
    for (int k = 0; k < PPT; ++k) { a0[k] = b20; a1[k] = b21; }

    const float4* __restrict__ W1v = reinterpret_cast<const float4*>(W1);
#pragma unroll 4
    for (int h = 0; h < 128; ++h) {
        const float4 w   = W1v[h];        // uniform, h-sequential -> wide s_load
        const float  bh  = fmaf(w.w, theta, b1[h]);   // uniform fold, 1 VALU op
        const float  w20 = W2[h];         // uniform, sequential
        const float  w21 = W2[128 + h];   // uniform, sequential
#pragma unroll
        for (int k = 0; k < PPT; ++k) {
            float hv = fmaf(x0[k], w.x, fmaf(x1[k], w.y, fmaf(x2[k], w.z, bh)));
            hv = fmaxf(hv, 0.0f);
            a0[k] = fmaf(hv, w20, a0[k]);
            a1[k] = fmaf(hv, w21, a1[k]);
        }
    }

#pragma unroll
    for (int k = 0; k < PPT; ++k) {
        *reinterpret_cast<float2*>(out_probs + 2 * p[k]) =
            make_float2(a0[k], a1[k]);                              // coalesced dwordx2
    }
}

extern "C" void kernel_launch(void* const* d_in, const int* in_sizes, int n_in,
                              void* d_out, int out_size, void* d_ws, size_t ws_size,
                              hipStream_t stream) {
    const float* input  = (const float*)d_in[0];
    const float* latent = (const float*)d_in[1];
    const float* W1     = (const float*)d_in[2];
    const float* b1     = (const float*)d_in[3];
    const float* W2     = (const float*)d_in[4];
    const float* b2     = (const float*)d_in[5];
    float* out = (float*)d_out;

    const int nblocks = NPTS / (BLOCK * PPT);   // 512
    hipLaunchKernelGGL(cubeflow_fused, dim3(nblocks), dim3(BLOCK), 0, stream,
                       input, latent, W1, b1, W2, b2, out);
}

// Round 3
// 78.973 us; speedup vs baseline: 1.0768x; 1.0610x over previous
//
#include <hip/hip_runtime.h>

#define BLOCK 512
#define NPTS (8 * 65536)
// Block handles 1024 points with 512 threads:
//   half = t>>8 (0/1) selects hidden-group (h in [half*64, half*64+64))
//   q    = t&255 ; each (half,q) processes points p(k) = blk*1024 + q + 256k, k=0..3
// Both halves load the same points (2nd group hits L1). Partial (a0,a1) are
// exchanged through LDS: each half writes partials for the k-set the OTHER
// half will store, so final stores are split evenly.
// Weights live in LDS as broadcasts: float4 {w0,w1,w2, b1+theta*w3}, float2 {W2r0,W2r1}.

__global__ __launch_bounds__(BLOCK, 4) void cubeflow_fused(
    const float* __restrict__ input,
    const float* __restrict__ latent,
    const float* __restrict__ W1,
    const float* __restrict__ b1,
    const float* __restrict__ W2,
    const float* __restrict__ b2,
    float* __restrict__ out)
{
    __shared__ float4 sW1[128];   // {w0,w1,w2, b1+theta*w3}
    __shared__ float2 sW2[128];   // {W2[0][h], W2[1][h]}
    __shared__ float4 sPart[BLOCK]; // partial {a0,a1} x 2 k's per thread

    const int t     = threadIdx.x;
    const int half  = t >> 8;       // 0 or 1
    const int q     = t & 255;
    const int base  = blockIdx.x * 1024;
    const int batch = base >> 16;                 // 64 blocks per batch
    const float theta = latent[batch] * 10.0f;    // uniform per block

    // ---- stage weights into LDS (threads 0..127) ----
    if (t < 128) {
        float4 w;
        w.x = W1[t * 4 + 0];
        w.y = W1[t * 4 + 1];
        w.z = W1[t * 4 + 2];
        w.w = fmaf(W1[t * 4 + 3], theta, b1[t]);
        sW1[t] = w;
        sW2[t] = make_float2(W2[t], W2[128 + t]);
    }

    // ---- load this thread's 4 points (both halves load same addresses) ----
    float x0[4], x1[4], x2[4];
    int p[4];
#pragma unroll
    for (int k = 0; k < 4; ++k) {
        p[k] = base + q + k * 256;
        const float* ip = input + 3 * p[k];
        x0[k] = ip[0];
        x1[k] = ip[1];
        x2[k] = ip[2];
    }

    float* __restrict__ out_eval  = out;             // NPTS
    float* __restrict__ out_con   = out + NPTS;      // NPTS*4
    float* __restrict__ out_probs = out + 5 * NPTS;  // NPTS*2

    // ---- eval + con for this half's k-set (half0: k0,1; half1: k2,3) ----
    {
        const float cth = cosf(theta);
        const float sth = sinf(theta);
        const int k0 = half * 2;
#pragma unroll
        for (int kk = 0; kk < 2; ++kk) {
            const int k = k0 + kk;
            const float d0 = x0[k] - theta;
            const float d1 = x1[k];
            const float d2 = x2[k];
            const float f1 = fmaf(1.4f * d0, d0, fmaf(1.4f * d1, d1, 0.2f * d2 * d2)) - 0.5f;
            const float c2x = fmaf(cth, d0,  sth * d1);
            const float c2y = fmaf(cth, d1, -sth * d0);
            const float c2z = d2 + 0.4f;
            const float f2 = fmaf(3.8f * c2x, c2x, fmaf(0.6f * c2y, c2y, 3.8f * c2z * c2z)) - 0.5f;
            const float c3x = fmaf(cth, d0, -sth * d1);
            const float c3y = fmaf(sth, d0,  cth * d1);
            const float c3z = d2 - 0.6f;
            const float f3 = fmaf(0.35f * c3x, c3x, fmaf(2.8f * c3y, c3y, 2.8f * c3z * c3z)) - 0.5f;
            out_eval[p[k]] = fminf(f1, fminf(f2, f3));
            *reinterpret_cast<float4*>(out_con + 4 * p[k]) =
                make_float4(x0[k], x1[k], x2[k], theta);
        }
    }

    __syncthreads();   // weights staged

    // ---- MLP over this half's 64 hidden units ----
    // half0 carries b2 in its partials; half1 starts at 0 (avoids double-add).
    float a0[4], a1[4];
    {
        const float i0 = half ? 0.0f : b2[0];
        const float i1 = half ? 0.0f : b2[1];
#pragma unroll
        for (int k = 0; k < 4; ++k) { a0[k] = i0; a1[k] = i1; }
    }

    const int hbeg = half * 64;
#pragma unroll 4
    for (int h = hbeg; h < hbeg + 64; ++h) {
        const float4 w  = sW1[h];   // LDS broadcast
        const float2 w2 = sW2[h];   // LDS broadcast
#pragma unroll
        for (int k = 0; k < 4; ++k) {
            float hv = fmaf(x0[k], w.x, fmaf(x1[k], w.y, fmaf(x2[k], w.z, w.w)));
            hv = fmaxf(hv, 0.0f);
            a0[k] = fmaf(hv, w2.x, a0[k]);
            a1[k] = fmaf(hv, w2.y, a1[k]);
        }
    }

    // ---- exchange partials: each half publishes the k-set the OTHER stores ----
    // halfX stores finals for k in {2X, 2X+1}; so it publishes {2(1-X), 2(1-X)+1}.
    const int kpub = (1 - half) * 2;
    sPart[t] = make_float4(a0[kpub], a1[kpub], a0[kpub + 1], a1[kpub + 1]);
    __syncthreads();

    const float4 other = sPart[(1 - half) * 256 + q];
    const int kst = half * 2;
    {
        const float r0 = a0[kst]     + other.x;
        const float r1 = a1[kst]     + other.y;
        const float r2 = a0[kst + 1] + other.z;
        const float r3 = a1[kst + 1] + other.w;
        *reinterpret_cast<float2*>(out_probs + 2 * p[kst])     = make_float2(r0, r1);
        *reinterpret_cast<float2*>(out_probs + 2 * p[kst + 1]) = make_float2(r2, r3);
    }
}

extern "C" void kernel_launch(void* const* d_in, const int* in_sizes, int n_in,
                              void* d_out, int out_size, void* d_ws, size_t ws_size,
                              hipStream_t stream) {
    const float* input  = (const float*)d_in[0];
    const float* latent = (const float*)d_in[1];
    const float* W1     = (const float*)d_in[2];
    const float* b1     = (const float*)d_in[3];
    const float* W2     = (const float*)d_in[4];
    const float* b2     = (const float*)d_in[5];
    float* out = (float*)d_out;

    const int nblocks = NPTS / 1024;   // 512
    hipLaunchKernelGGL(cubeflow_fused, dim3(nblocks), dim3(BLOCK), 0, stream,
                       input, latent, W1, b1, W2, b2, out);
}